// Round 1
// baseline (108.202 us; speedup 1.0000x reference)
//
#include <hip/hip_runtime.h>

// LearnedEvictionModel, MI355X.
// Key transform: scores depend only on the token's embedding row -> precompute
// score_table[64]. Layer-1 of the read head is linear in table rows ->
// precompute Q1b[v][k] = embed[v]@rh_w1[:64,k] + rh_b1[k] and
// M1s[v][k] = (1/8) embed[v]@rh_w1[64:,k]. The scan becomes integer slot
// bookkeeping; only layer-2 (64x64 per batch) is real compute.

#define SEQ_LEN 32
#define MEM_SLOTS 8

// ws float layout: [0,64) scores | [64, 64+4096) Q1b | [4160, 4160+4096) M1s
#define WS_SCORE 0
#define WS_Q1B   64
#define WS_M1S   (64 + 4096)

__global__ __launch_bounds__(256) void lem_precompute(
    const float* __restrict__ embed,
    const float* __restrict__ sc_w1, const float* __restrict__ sc_b1,
    const float* __restrict__ sc_w2, const float* __restrict__ sc_b2,
    const float* __restrict__ rh_w1, const float* __restrict__ rh_b1,
    float* __restrict__ ws)
{
    const int t = threadIdx.x;
    if (blockIdx.x < 16) {
        // Q1b / M1s tables: one (v,k) pair per thread, 4096 pairs over 16 blocks.
        const int p = blockIdx.x * 256 + t;     // 0..4095
        const int v = p >> 6, k = p & 63;
        const float* e = embed + v * 64;
        float q = rh_b1[k];
        float m = 0.f;
        #pragma unroll 8
        for (int i = 0; i < 64; ++i) {
            q = fmaf(e[i], rh_w1[i * 64 + k], q);
            m = fmaf(e[i], rh_w1[(64 + i) * 64 + k], m);
        }
        ws[WS_Q1B + p] = q;
        ws[WS_M1S + p] = m * 0.125f;
    } else {
        // token scores: 64 tokens x 32 hidden units = 2048 subjobs
        __shared__ float part[2048];
        #pragma unroll
        for (int r = 0; r < 8; ++r) {
            const int s = r * 256 + t;          // 0..2047
            const int v = s >> 5, k = s & 31;
            const float* e = embed + v * 64;
            float a = sc_b1[k];
            #pragma unroll 8
            for (int i = 0; i < 64; ++i) a = fmaf(e[i], sc_w1[i * 32 + k], a);
            a = fmaxf(a, 0.f);
            part[s] = a * sc_w2[k];
        }
        __syncthreads();
        if (t < 64) {
            float s = sc_b2[0];
            for (int k = 0; k < 32; ++k) s += part[t * 32 + k];
            ws[WS_SCORE + t] = s;
        }
    }
}

__global__ __launch_bounds__(256) void lem_main(
    const int* __restrict__ seqs, const int* __restrict__ qtok,
    const float* __restrict__ rh_w2, const float* __restrict__ rh_b2,
    const float* __restrict__ ws, float* __restrict__ out)
{
    __shared__ float QM[4096];                 // Q1b (includes rh_b1)
    __shared__ float MM[4096];                 // M1s (includes 1/8 scale)
    __shared__ float score_s[64];
    __shared__ unsigned long long tok_s[64];   // 8 surviving tokens, packed bytes
    __shared__ float hh[64 * 65];              // relu(layer1), stride 65: 65%32==1 -> conflict-free

    const int t = threadIdx.x;
    const int gbase = blockIdx.x * 64;

    // -------- stage tables --------
    for (int i = t; i < 4096; i += 256) {
        QM[i] = ws[WS_Q1B + i];
        MM[i] = ws[WS_M1S + i];
    }
    if (t < 64) score_s[t] = ws[WS_SCORE + t];
    __syncthreads();

    // -------- phase A: eviction scan (wave 0, one batch per lane) --------
    if (t < 64) {
        const int b = gbase + t;
        int tk[SEQ_LEN];
        const int4* sq4 = (const int4*)(seqs + (long long)b * SEQ_LEN);
        #pragma unroll
        for (int r = 0; r < SEQ_LEN / 4; ++r) {
            int4 v = sq4[r];
            tk[r * 4 + 0] = v.x; tk[r * 4 + 1] = v.y;
            tk[r * 4 + 2] = v.z; tk[r * 4 + 3] = v.w;
        }
        int tok[MEM_SLOTS]; float sc[MEM_SLOTS];
        #pragma unroll
        for (int j = 0; j < MEM_SLOTS; ++j) tok[j] = tk[j];
        #pragma unroll
        for (int j = 0; j < MEM_SLOTS; ++j) sc[j] = score_s[tok[j]];
        #pragma unroll
        for (int step = MEM_SLOTS; step < SEQ_LEN - 1; ++step) {
            const int nt = tk[step];
            const float ns = score_s[nt];
            // first-index argmin (strict <) == jnp.argmin tie rule
            float bv = sc[0]; int be = 0;
            #pragma unroll
            for (int j = 1; j < MEM_SLOTS; ++j) {
                const bool lt = sc[j] < bv;
                bv = lt ? sc[j] : bv;
                be = lt ? j : be;
            }
            #pragma unroll
            for (int j = 0; j < MEM_SLOTS - 1; ++j) {
                const bool take = (j >= be);
                sc[j]  = take ? sc[j + 1]  : sc[j];
                tok[j] = take ? tok[j + 1] : tok[j];
            }
            sc[MEM_SLOTS - 1] = ns;
            tok[MEM_SLOTS - 1] = nt;
        }
        unsigned long long pk = 0ull;
        #pragma unroll
        for (int j = 0; j < MEM_SLOTS; ++j)
            pk |= (unsigned long long)(tok[j] & 255) << (8 * j);
        tok_s[t] = pk;
    }
    __syncthreads();

    // -------- phase B: read head --------
    const int lane = t & 63;
    const int w = t >> 6;          // wave 0..3
    const int k0 = w * 16;         // this wave's 16-wide k-slice (layer1) / m-slice (layer2)
    const int b = lane;            // batch within block (lane = batch)
    const int qb = qtok[gbase + b];
    const unsigned long long pk = tok_s[b];

    // layer 1: hh[b][k0..k0+16) = relu(Q1b[qb] + sum_j M1s[tok_j])
    float acc[16];
    const float4* QM4 = (const float4*)QM;
    const float4* MM4 = (const float4*)MM;
    {
        const int qbase = (qb * 64 + k0) >> 2;
        #pragma unroll
        for (int j4 = 0; j4 < 4; ++j4) {
            float4 v = QM4[qbase + j4];
            acc[j4 * 4 + 0] = v.x; acc[j4 * 4 + 1] = v.y;
            acc[j4 * 4 + 2] = v.z; acc[j4 * 4 + 3] = v.w;
        }
    }
    #pragma unroll
    for (int j = 0; j < MEM_SLOTS; ++j) {
        const int tkn = (int)((pk >> (8 * j)) & 255);
        const int mb = (tkn * 64 + k0) >> 2;
        #pragma unroll
        for (int j4 = 0; j4 < 4; ++j4) {
            float4 v = MM4[mb + j4];
            acc[j4 * 4 + 0] += v.x; acc[j4 * 4 + 1] += v.y;
            acc[j4 * 4 + 2] += v.z; acc[j4 * 4 + 3] += v.w;
        }
    }
    #pragma unroll
    for (int j = 0; j < 16; ++j)
        hh[b * 65 + k0 + j] = fmaxf(acc[j], 0.f);
    __syncthreads();

    // layer 2: out[b][m0..m0+16), weights via wave-uniform (scalar) loads
    const int m0 = __builtin_amdgcn_readfirstlane(k0);
    float o[16];
    #pragma unroll
    for (int j = 0; j < 16; ++j) o[j] = rh_b2[m0 + j];
    #pragma unroll 4
    for (int k = 0; k < 64; ++k) {
        const float h = hh[b * 65 + k];
        #pragma unroll
        for (int j = 0; j < 16; ++j)
            o[j] = fmaf(h, rh_w2[k * 64 + m0 + j], o[j]);
    }
    float4* op4 = (float4*)(out + (long long)(gbase + b) * 64 + m0);
    #pragma unroll
    for (int j4 = 0; j4 < 4; ++j4)
        op4[j4] = make_float4(o[j4 * 4 + 0], o[j4 * 4 + 1],
                              o[j4 * 4 + 2], o[j4 * 4 + 3]);
}

extern "C" void kernel_launch(void* const* d_in, const int* in_sizes, int n_in,
                              void* d_out, int out_size, void* d_ws, size_t ws_size,
                              hipStream_t stream)
{
    const int*   seqs   = (const int*)d_in[0];
    const int*   qtok   = (const int*)d_in[1];
    const float* embed  = (const float*)d_in[2];
    const float* sc_w1  = (const float*)d_in[3];
    const float* sc_b1  = (const float*)d_in[4];
    const float* sc_w2  = (const float*)d_in[5];
    const float* sc_b2  = (const float*)d_in[6];
    const float* rh_w1  = (const float*)d_in[7];
    const float* rh_b1  = (const float*)d_in[8];
    const float* rh_w2  = (const float*)d_in[9];
    const float* rh_b2  = (const float*)d_in[10];
    float* out = (float*)d_out;
    float* ws  = (float*)d_ws;

    const int B = in_sizes[1];   // 32768

    lem_precompute<<<17, 256, 0, stream>>>(embed, sc_w1, sc_b1, sc_w2, sc_b2,
                                           rh_w1, rh_b1, ws);
    lem_main<<<B / 64, 256, 0, stream>>>(seqs, qtok, rh_w2, rh_b2, ws, out);
}

// Round 2
// 101.475 us; speedup vs baseline: 1.0663x; 1.0663x over previous
//
#include <hip/hip_runtime.h>

// LearnedEvictionModel, MI355X.
// Key transform: scores depend only on the token's embedding row -> precompute
// score_table[64]. Layer-1 of the read head is linear in table rows ->
// precompute Q1b[v][k] = embed[v]@rh_w1[:64,k] + rh_b1[k] (row-major) and
// M1sT[k][v] = (1/8) embed[v]@rh_w1[64:,k] (TRANSPOSED: gather addr k*64+tkn
// -> bank = tkn%32, random tokens -> conflict-free; row-major rows start at
// bank 0 for every token -> 16-way conflict). The scan is integer slot
// bookkeeping; only layer-2 (64x64 per batch) is real compute.

#define SEQ_LEN 32
#define MEM_SLOTS 8

// ws float layout: [0,64) scores | [64, 64+4096) Q1b row-major | M1sT transposed
#define WS_SCORE 0
#define WS_Q1B   64
#define WS_M1T   (64 + 4096)

__global__ __launch_bounds__(256) void lem_precompute(
    const float* __restrict__ embed,
    const float* __restrict__ sc_w1, const float* __restrict__ sc_b1,
    const float* __restrict__ sc_w2, const float* __restrict__ sc_b2,
    const float* __restrict__ rh_w1, const float* __restrict__ rh_b1,
    float* __restrict__ ws)
{
    const int t = threadIdx.x;
    if (blockIdx.x < 16) {
        // Q1b / M1sT tables: one (v,k) pair per thread, 4096 pairs over 16 blocks.
        const int p = blockIdx.x * 256 + t;     // 0..4095
        const int v = p >> 6, k = p & 63;
        const float* e = embed + v * 64;
        float q = rh_b1[k];
        float m = 0.f;
        #pragma unroll 8
        for (int i = 0; i < 64; ++i) {
            q = fmaf(e[i], rh_w1[i * 64 + k], q);
            m = fmaf(e[i], rh_w1[(64 + i) * 64 + k], m);
        }
        ws[WS_Q1B + v * 64 + k] = q;            // row-major
        ws[WS_M1T + k * 64 + v] = m * 0.125f;   // transposed
    } else {
        // token scores: 64 tokens x 32 hidden units = 2048 subjobs
        __shared__ float part[2048];
        #pragma unroll
        for (int r = 0; r < 8; ++r) {
            const int s = r * 256 + t;          // 0..2047
            const int v = s >> 5, k = s & 31;
            const float* e = embed + v * 64;
            float a = sc_b1[k];
            #pragma unroll 8
            for (int i = 0; i < 64; ++i) a = fmaf(e[i], sc_w1[i * 32 + k], a);
            a = fmaxf(a, 0.f);
            part[s] = a * sc_w2[k];
        }
        __syncthreads();
        if (t < 64) {
            float s = sc_b2[0];
            for (int k = 0; k < 32; ++k) s += part[t * 32 + k];
            ws[WS_SCORE + t] = s;
        }
    }
}

__global__ __launch_bounds__(256) void lem_main(
    const int* __restrict__ seqs, const int* __restrict__ qtok,
    const float* __restrict__ rh_w2, const float* __restrict__ rh_b2,
    const float* __restrict__ ws, float* __restrict__ out)
{
    __shared__ float MT[4096];                 // M1sT[k][v] (1/8 scale baked in)
    __shared__ float score_s[64];
    __shared__ unsigned long long tok_s[64];   // 8 surviving tokens, packed bytes
    __shared__ float hh[4096];                 // relu(layer1), [k][b]: conflict-free both ways

    const int t = threadIdx.x;
    const int gbase = blockIdx.x * 64;

    // -------- stage M-table + scores (Q1b read straight from L2-hot ws) -----
    for (int i = t; i < 4096; i += 256) MT[i] = ws[WS_M1T + i];
    if (t < 64) score_s[t] = ws[WS_SCORE + t];
    __syncthreads();

    // -------- phase A: eviction scan (wave 0, one batch per lane) --------
    if (t < 64) {
        const int b = gbase + t;
        int tk[SEQ_LEN];
        const int4* sq4 = (const int4*)(seqs + (long long)b * SEQ_LEN);
        #pragma unroll
        for (int r = 0; r < SEQ_LEN / 4; ++r) {
            int4 v = sq4[r];
            tk[r * 4 + 0] = v.x; tk[r * 4 + 1] = v.y;
            tk[r * 4 + 2] = v.z; tk[r * 4 + 3] = v.w;
        }
        int tok[MEM_SLOTS]; float sc[MEM_SLOTS];
        #pragma unroll
        for (int j = 0; j < MEM_SLOTS; ++j) tok[j] = tk[j];
        #pragma unroll
        for (int j = 0; j < MEM_SLOTS; ++j) sc[j] = score_s[tok[j]];
        #pragma unroll
        for (int step = MEM_SLOTS; step < SEQ_LEN - 1; ++step) {
            const int nt = tk[step];
            const float ns = score_s[nt];
            // first-index argmin (strict <) == jnp.argmin tie rule
            float bv = sc[0]; int be = 0;
            #pragma unroll
            for (int j = 1; j < MEM_SLOTS; ++j) {
                const bool lt = sc[j] < bv;
                bv = lt ? sc[j] : bv;
                be = lt ? j : be;
            }
            #pragma unroll
            for (int j = 0; j < MEM_SLOTS - 1; ++j) {
                const bool take = (j >= be);
                sc[j]  = take ? sc[j + 1]  : sc[j];
                tok[j] = take ? tok[j + 1] : tok[j];
            }
            sc[MEM_SLOTS - 1] = ns;
            tok[MEM_SLOTS - 1] = nt;
        }
        unsigned long long pk = 0ull;
        #pragma unroll
        for (int j = 0; j < MEM_SLOTS; ++j)
            pk |= (unsigned long long)(tok[j] & 255) << (8 * j);
        tok_s[t] = pk;
    }
    __syncthreads();

    // -------- phase B: read head --------
    const int lane = t & 63;
    const int w = t >> 6;          // wave 0..3
    const int k0 = w * 16;         // this wave's 16-wide k-slice / m-slice
    const int b = lane;            // batch within block (lane = batch)
    const int qb = qtok[gbase + b];
    const unsigned long long pk = tok_s[b];

    // layer 1: hh[k0..k0+16)[b] = relu(Q1b[qb] + sum_j M1sT[.][tok_j])
    float acc[16];
    {   // Q row gather from global ws (16 KB table, L2/L1-hot)
        const float4* Q4 = (const float4*)(ws + WS_Q1B);
        const int qbase = (qb * 64 + k0) >> 2;
        #pragma unroll
        for (int j4 = 0; j4 < 4; ++j4) {
            float4 v = Q4[qbase + j4];
            acc[j4 * 4 + 0] = v.x; acc[j4 * 4 + 1] = v.y;
            acc[j4 * 4 + 2] = v.z; acc[j4 * 4 + 3] = v.w;
        }
    }
    #pragma unroll
    for (int j = 0; j < MEM_SLOTS; ++j) {
        const int tkn = (int)((pk >> (8 * j)) & 255);
        #pragma unroll
        for (int jj = 0; jj < 16; ++jj)
            acc[jj] += MT[(k0 + jj) * 64 + tkn];   // bank = tkn%32: conflict-free
    }
    #pragma unroll
    for (int jj = 0; jj < 16; ++jj)
        hh[(k0 + jj) * 64 + b] = fmaxf(acc[jj], 0.f);  // lanes consecutive: conflict-free
    __syncthreads();

    // layer 2: out[b][m0..m0+16), weights via wave-uniform (scalar) loads
    const int m0 = __builtin_amdgcn_readfirstlane(k0);
    float o[16];
    #pragma unroll
    for (int j = 0; j < 16; ++j) o[j] = rh_b2[m0 + j];
    #pragma unroll 4
    for (int k = 0; k < 64; ++k) {
        const float h = hh[k * 64 + b];            // lanes consecutive: conflict-free
        #pragma unroll
        for (int j = 0; j < 16; ++j)
            o[j] = fmaf(h, rh_w2[k * 64 + m0 + j], o[j]);
    }
    float4* op4 = (float4*)(out + (long long)(gbase + b) * 64 + m0);
    #pragma unroll
    for (int j4 = 0; j4 < 4; ++j4)
        op4[j4] = make_float4(o[j4 * 4 + 0], o[j4 * 4 + 1],
                              o[j4 * 4 + 2], o[j4 * 4 + 3]);
}

extern "C" void kernel_launch(void* const* d_in, const int* in_sizes, int n_in,
                              void* d_out, int out_size, void* d_ws, size_t ws_size,
                              hipStream_t stream)
{
    const int*   seqs   = (const int*)d_in[0];
    const int*   qtok   = (const int*)d_in[1];
    const float* embed  = (const float*)d_in[2];
    const float* sc_w1  = (const float*)d_in[3];
    const float* sc_b1  = (const float*)d_in[4];
    const float* sc_w2  = (const float*)d_in[5];
    const float* sc_b2  = (const float*)d_in[6];
    const float* rh_w1  = (const float*)d_in[7];
    const float* rh_b1  = (const float*)d_in[8];
    const float* rh_w2  = (const float*)d_in[9];
    const float* rh_b2  = (const float*)d_in[10];
    float* out = (float*)d_out;
    float* ws  = (float*)d_ws;

    const int B = in_sizes[1];   // 32768

    lem_precompute<<<17, 256, 0, stream>>>(embed, sc_w1, sc_b1, sc_w2, sc_b2,
                                           rh_w1, rh_b1, ws);
    lem_main<<<B / 64, 256, 0, stream>>>(seqs, qtok, rh_w2, rh_b2, ws, out);
}

// Round 3
// 95.197 us; speedup vs baseline: 1.1366x; 1.0660x over previous
//
#include <hip/hip_runtime.h>

// LearnedEvictionModel, MI355X.
// Transforms:
//  - Eviction scores depend only on the token's embedding row -> score_table[64].
//  - Layer-1 of the read head is linear in table rows -> precompute
//    Q1b[v][k] = embed[v]@rh_w1[:64,k] + rh_b1[k] (row-major) and
//    M1sT[k][v] = (1/8) embed[v]@rh_w1[64:,k] (transposed -> LDS gather addr
//    k*64+tkn, bank = tkn%32, random tokens -> conflict-free).
//  - Layer-2 (64x64x64 per block) runs on MFMA (bf16 in, fp32 acc): one
//    32x32 tile per wave x 4 K-steps of v_mfma_f32_32x32x16_bf16.
//    rh_w2 is pre-swizzled into B-fragment order (bf16 pairs) by precompute;
//    h is produced in packed-bf16 [k/2][b] LDS layout (A-frag = ds_read_b32 x4).
//  - Wave 0 scans while waves 1-3 stage MT / prefetch B-frags: 2 barriers total.

#define SEQ_LEN 32
#define MEM_SLOTS 8

// ws float-word layout:
//   [0,64)            score table
//   [64, 64+4096)     Q1b row-major (rh_b1 baked in)
//   [8256- wait, see] M1sT transposed (1/8 baked in)
//   [WS_W2B, +2048)   rh_w2 as bf16 pairs, pre-swizzled B-fragment order
#define WS_SCORE 0
#define WS_Q1B   64
#define WS_M1T   (64 + 4096)
#define WS_W2B   (64 + 4096 + 4096)

typedef __attribute__((ext_vector_type(8)))  short short8;
typedef __attribute__((ext_vector_type(16))) float floatx16;

__device__ __forceinline__ uint32_t bf16rtne(float f) {
    uint32_t u = __float_as_uint(f);
    return (u + 0x7FFFu + ((u >> 16) & 1u)) >> 16;
}

__global__ __launch_bounds__(256) void lem_precompute(
    const float* __restrict__ embed,
    const float* __restrict__ sc_w1, const float* __restrict__ sc_b1,
    const float* __restrict__ sc_w2, const float* __restrict__ sc_b2,
    const float* __restrict__ rh_w1, const float* __restrict__ rh_b1,
    const float* __restrict__ rh_w2,
    float* __restrict__ ws)
{
    const int t = threadIdx.x;
    if (blockIdx.x < 16) {
        // Q1b / M1sT tables: one (v,k) pair per thread, 4096 pairs over 16 blocks.
        const int p = blockIdx.x * 256 + t;     // 0..4095
        const int v = p >> 6, k = p & 63;
        const float* e = embed + v * 64;
        float q = rh_b1[k];
        float m = 0.f;
        #pragma unroll 8
        for (int i = 0; i < 64; ++i) {
            q = fmaf(e[i], rh_w1[i * 64 + k], q);
            m = fmaf(e[i], rh_w1[(64 + i) * 64 + k], m);
        }
        ws[WS_Q1B + v * 64 + k] = q;            // row-major
        ws[WS_M1T + k * 64 + v] = m * 0.125f;   // transposed
    } else {
        // (a) token scores: 64 tokens x 32 hidden units = 2048 subjobs
        __shared__ float part[2048];
        #pragma unroll
        for (int r = 0; r < 8; ++r) {
            const int s = r * 256 + t;          // 0..2047
            const int v = s >> 5, k = s & 31;
            const float* e = embed + v * 64;
            float a = sc_b1[k];
            #pragma unroll 8
            for (int i = 0; i < 64; ++i) a = fmaf(e[i], sc_w1[i * 32 + k], a);
            a = fmaxf(a, 0.f);
            part[s] = a * sc_w2[k];
        }
        // (b) rh_w2 -> bf16, pre-swizzled B-fragment order.
        //     storage idx sidx = tile*256 + lane*4 + d, tile = ktile*2 + tile_n;
        //     dword holds (k, k+1) bf16 pair, k = ktile*16 + (lane>>5)*8 + 2d,
        //     n = tile_n*32 + (lane&31).
        uint32_t* wb = (uint32_t*)ws + WS_W2B;
        #pragma unroll
        for (int r = 0; r < 8; ++r) {
            const int sidx = r * 256 + t;       // 0..2047
            const int d = sidx & 3;
            const int ln = (sidx >> 2) & 63;
            const int tile = sidx >> 8;         // 0..7
            const int ktile = tile >> 1, tn = tile & 1;
            const int k = ktile * 16 + (ln >> 5) * 8 + 2 * d;
            const int n = tn * 32 + (ln & 31);
            const uint32_t lo = bf16rtne(rh_w2[k * 64 + n]);
            const uint32_t hi = bf16rtne(rh_w2[(k + 1) * 64 + n]);
            wb[sidx] = lo | (hi << 16);
        }
        __syncthreads();
        if (t < 64) {
            float s = sc_b2[0];
            for (int k = 0; k < 32; ++k) s += part[t * 32 + k];
            ws[WS_SCORE + t] = s;
        }
    }
}

__global__ __launch_bounds__(256) void lem_main(
    const int* __restrict__ seqs, const int* __restrict__ qtok,
    const float* __restrict__ rh_b2,
    const float* __restrict__ ws, float* __restrict__ out)
{
    __shared__ float MT[4096];                 // M1sT[k][v]
    __shared__ float score_s[64];
    __shared__ unsigned long long tok_s[64];   // 8 surviving tokens, packed bytes
    __shared__ uint32_t hh2[32 * 64];          // h as bf16 pairs, [k/2][b]

    const int t = threadIdx.x;
    const int gbase = blockIdx.x * 64;
    const int lane = t & 63;
    const int w = t >> 6;                      // wave 0..3
    const int col = t & 31;                    // n within tile / batch within tile
    const int half = (t >> 5) & 1;
    const int tile_n = w & 1;                  // out-dim half
    const int tile_m = w >> 1;                 // batch half

    // -------- early prefetch: B fragments + bias (hidden behind scan) --------
    uint4 bq[4];
    const uint4* B4 = (const uint4*)((const uint32_t*)ws + WS_W2B);
    #pragma unroll
    for (int kt = 0; kt < 4; ++kt)
        bq[kt] = B4[(kt * 2 + tile_n) * 64 + lane];
    const float bias = rh_b2[tile_n * 32 + col];

    if (w == 0) {
        // -------- wave 0: scores + eviction scan (one batch per lane) --------
        score_s[lane] = ws[WS_SCORE + lane];   // wave-internal LDS: no barrier needed
        const int b = gbase + lane;
        int tk[SEQ_LEN];
        const int4* sq4 = (const int4*)(seqs + (long long)b * SEQ_LEN);
        #pragma unroll
        for (int r = 0; r < SEQ_LEN / 4; ++r) {
            int4 v = sq4[r];
            tk[r * 4 + 0] = v.x; tk[r * 4 + 1] = v.y;
            tk[r * 4 + 2] = v.z; tk[r * 4 + 3] = v.w;
        }
        int tok[MEM_SLOTS]; float sc[MEM_SLOTS];
        #pragma unroll
        for (int j = 0; j < MEM_SLOTS; ++j) tok[j] = tk[j];
        #pragma unroll
        for (int j = 0; j < MEM_SLOTS; ++j) sc[j] = score_s[tok[j]];
        #pragma unroll
        for (int step = MEM_SLOTS; step < SEQ_LEN - 1; ++step) {
            const int nt = tk[step];
            const float ns = score_s[nt];
            // first-index argmin (strict <) == jnp.argmin tie rule
            float bv = sc[0]; int be = 0;
            #pragma unroll
            for (int j = 1; j < MEM_SLOTS; ++j) {
                const bool lt = sc[j] < bv;
                bv = lt ? sc[j] : bv;
                be = lt ? j : be;
            }
            #pragma unroll
            for (int j = 0; j < MEM_SLOTS - 1; ++j) {
                const bool take = (j >= be);
                sc[j]  = take ? sc[j + 1]  : sc[j];
                tok[j] = take ? tok[j + 1] : tok[j];
            }
            sc[MEM_SLOTS - 1] = ns;
            tok[MEM_SLOTS - 1] = nt;
        }
        unsigned long long pk = 0ull;
        #pragma unroll
        for (int j = 0; j < MEM_SLOTS; ++j)
            pk |= (unsigned long long)(tok[j] & 255) << (8 * j);
        tok_s[lane] = pk;
    } else {
        // -------- waves 1-3: stage MT concurrently with the scan --------
        const float4* src = (const float4*)(ws + WS_M1T);
        float4* dst = (float4*)MT;
        for (int i = t - 64; i < 1024; i += 192) dst[i] = src[i];
    }
    __syncthreads();

    // -------- layer 1: h[k0..k0+16)[b] = relu(Q1b[qb] + sum_j M1sT[.][tok_j])
    const int b = lane;                        // batch within block
    const int k0 = w * 16;                     // this wave's k-slice
    const int qb = qtok[gbase + b];
    const unsigned long long pk = tok_s[b];

    float acc[16];
    {   // Q row from global ws (16 KB, L1/L2-hot)
        const float4* Q4 = (const float4*)(ws + WS_Q1B);
        const int qbase = (qb * 64 + k0) >> 2;
        #pragma unroll
        for (int j4 = 0; j4 < 4; ++j4) {
            float4 v = Q4[qbase + j4];
            acc[j4 * 4 + 0] = v.x; acc[j4 * 4 + 1] = v.y;
            acc[j4 * 4 + 2] = v.z; acc[j4 * 4 + 3] = v.w;
        }
    }
    #pragma unroll
    for (int j = 0; j < MEM_SLOTS; ++j) {
        const int tkn = (int)((pk >> (8 * j)) & 255);
        #pragma unroll
        for (int jj = 0; jj < 16; ++jj)
            acc[jj] += MT[(k0 + jj) * 64 + tkn];   // bank = tkn%32: conflict-free
    }
    // relu -> bf16 pairs -> hh2[k/2][b] (banks = b%32: conflict-free)
    #pragma unroll
    for (int j = 0; j < 8; ++j) {
        const uint32_t lo = bf16rtne(fmaxf(acc[2 * j + 0], 0.f));
        const uint32_t hi = bf16rtne(fmaxf(acc[2 * j + 1], 0.f));
        hh2[(w * 8 + j) * 64 + b] = lo | (hi << 16);
    }
    __syncthreads();

    // -------- layer 2: MFMA. C[m=batch(32)][n=out(32)] per wave, 4 K-steps.
    floatx16 oacc;
    #pragma unroll
    for (int i = 0; i < 16; ++i) oacc[i] = bias;

    union U8 { uint32_t u[4]; short8 s; };
    #pragma unroll
    for (int kt = 0; kt < 4; ++kt) {
        U8 a;
        #pragma unroll
        for (int d = 0; d < 4; ++d)
            a.u[d] = hh2[(kt * 8 + half * 4 + d) * 64 + (tile_m * 32 + col)];
        U8 bb;
        bb.u[0] = bq[kt].x; bb.u[1] = bq[kt].y;
        bb.u[2] = bq[kt].z; bb.u[3] = bq[kt].w;
        oacc = __builtin_amdgcn_mfma_f32_32x32x16_bf16(a.s, bb.s, oacc, 0, 0, 0);
    }

    // store: row=(reg&3)+8*(reg>>2)+4*half, col=lane&31 (m74/m101-verified)
    #pragma unroll
    for (int reg = 0; reg < 16; ++reg) {
        const int row = (reg & 3) + 8 * (reg >> 2) + 4 * half;
        out[(long long)(gbase + tile_m * 32 + row) * 64 + tile_n * 32 + col] = oacc[reg];
    }
}

extern "C" void kernel_launch(void* const* d_in, const int* in_sizes, int n_in,
                              void* d_out, int out_size, void* d_ws, size_t ws_size,
                              hipStream_t stream)
{
    const int*   seqs   = (const int*)d_in[0];
    const int*   qtok   = (const int*)d_in[1];
    const float* embed  = (const float*)d_in[2];
    const float* sc_w1  = (const float*)d_in[3];
    const float* sc_b1  = (const float*)d_in[4];
    const float* sc_w2  = (const float*)d_in[5];
    const float* sc_b2  = (const float*)d_in[6];
    const float* rh_w1  = (const float*)d_in[7];
    const float* rh_b1  = (const float*)d_in[8];
    const float* rh_w2  = (const float*)d_in[9];
    const float* rh_b2  = (const float*)d_in[10];
    float* out = (float*)d_out;
    float* ws  = (float*)d_ws;

    const int B = in_sizes[1];   // 32768

    lem_precompute<<<17, 256, 0, stream>>>(embed, sc_w1, sc_b1, sc_w2, sc_b2,
                                           rh_w1, rh_b1, rh_w2, ws);
    lem_main<<<B / 64, 256, 0, stream>>>(seqs, qtok, rh_b2, ws, out);
}

// Round 4
// 93.079 us; speedup vs baseline: 1.1625x; 1.0227x over previous
//
#include <hip/hip_runtime.h>

// LearnedEvictionModel, MI355X.
// Transforms:
//  - Eviction scores depend only on the token's embedding row -> score_table[64].
//  - Layer-1 of the read head is linear in table rows -> precompute
//    Q1b[v][k] = embed[v]@rh_w1[:64,k] + rh_b1[k] (fp32, row-major) and
//    MT2[k/2][v] = packed bf16 pair of (1/8)*embed[v]@rh_w1[64:,k] for k,k+1
//    (transposed + pair-packed: LDS gather addr (k/2)*64+tkn -> bank=tkn%32,
//    conflict-free, and HALF the ds_read count of fp32).
//  - Layer-2 (64x64x64 per block) on MFMA bf16: one 32x32 tile/wave x 4 K-steps.
//    rh_w2 pre-swizzled into B-fragment order; h produced in packed-bf16
//    [k/2][b] LDS layout.
//  - Wave 0 scans while waves 1-3 stage MT2; Q-row gather + B-frags prefetched
//    pre-barrier (hidden behind the scan). 2 barriers total.

#define SEQ_LEN 32
#define MEM_SLOTS 8

// ws 32-bit-word layout:
//   [0,64)       score table (fp32)
//   [64,4160)    Q1b row-major fp32 (rh_b1 baked in)
//   [4160,6208)  MT2 packed bf16 pairs (1/8 baked in), [k/2][v]
//   [6208,8256)  rh_w2 bf16 pairs, pre-swizzled B-fragment order
#define WS_SCORE 0
#define WS_Q1B   64
#define WS_M2P   (64 + 4096)
#define WS_W2B   (64 + 4096 + 2048)

typedef __attribute__((ext_vector_type(8)))  short short8;
typedef __attribute__((ext_vector_type(16))) float floatx16;

__device__ __forceinline__ uint32_t bf16rtne(float f) {
    uint32_t u = __float_as_uint(f);
    return (u + 0x7FFFu + ((u >> 16) & 1u)) >> 16;
}

__global__ __launch_bounds__(256) void lem_precompute(
    const float* __restrict__ embed,
    const float* __restrict__ sc_w1, const float* __restrict__ sc_b1,
    const float* __restrict__ sc_w2, const float* __restrict__ sc_b2,
    const float* __restrict__ rh_w1, const float* __restrict__ rh_b1,
    const float* __restrict__ rh_w2,
    float* __restrict__ ws)
{
    const int t = threadIdx.x;
    const int blk = blockIdx.x;
    if (blk < 16) {
        // Q1b: one (v,k) per thread, 4096 over 16 blocks.
        const int p = blk * 256 + t;
        const int v = p >> 6, k = p & 63;
        const float* e = embed + v * 64;
        float q = rh_b1[k];
        #pragma unroll 8
        for (int i = 0; i < 64; ++i) q = fmaf(e[i], rh_w1[i * 64 + k], q);
        ws[WS_Q1B + v * 64 + k] = q;
    } else if (blk < 24) {
        // MT2: one (v, kpair) per thread, 2048 over 8 blocks.
        const int p = (blk - 16) * 256 + t;
        const int v = p >> 5, j = p & 31;       // kpair j -> k = 2j, 2j+1
        const float* e = embed + v * 64;
        float m0 = 0.f, m1 = 0.f;
        #pragma unroll 8
        for (int i = 0; i < 64; ++i) {
            const float ei = e[i];
            m0 = fmaf(ei, rh_w1[(64 + i) * 64 + 2 * j + 0], m0);
            m1 = fmaf(ei, rh_w1[(64 + i) * 64 + 2 * j + 1], m1);
        }
        ((uint32_t*)ws)[WS_M2P + j * 64 + v] =
            bf16rtne(m0 * 0.125f) | (bf16rtne(m1 * 0.125f) << 16);
    } else {
        // (a) token scores: 64 tokens x 32 hidden = 2048 subjobs
        __shared__ float part[2048];
        #pragma unroll
        for (int r = 0; r < 8; ++r) {
            const int s = r * 256 + t;
            const int v = s >> 5, k = s & 31;
            const float* e = embed + v * 64;
            float a = sc_b1[k];
            #pragma unroll 8
            for (int i = 0; i < 64; ++i) a = fmaf(e[i], sc_w1[i * 32 + k], a);
            a = fmaxf(a, 0.f);
            part[s] = a * sc_w2[k];
        }
        // (b) rh_w2 -> bf16, pre-swizzled B-fragment order:
        //     sidx = tile*256 + lane*4 + d, tile = ktile*2 + tile_n;
        //     dword = (k, k+1), k = ktile*16 + (lane>>5)*8 + 2d, n = tile_n*32 + (lane&31)
        uint32_t* wb = (uint32_t*)ws + WS_W2B;
        #pragma unroll
        for (int r = 0; r < 8; ++r) {
            const int sidx = r * 256 + t;
            const int d = sidx & 3;
            const int ln = (sidx >> 2) & 63;
            const int tile = sidx >> 8;
            const int ktile = tile >> 1, tn = tile & 1;
            const int k = ktile * 16 + (ln >> 5) * 8 + 2 * d;
            const int n = tn * 32 + (ln & 31);
            wb[sidx] = bf16rtne(rh_w2[k * 64 + n]) |
                       (bf16rtne(rh_w2[(k + 1) * 64 + n]) << 16);
        }
        __syncthreads();
        if (t < 64) {
            float s = sc_b2[0];
            for (int k = 0; k < 32; ++k) s += part[t * 32 + k];
            ws[WS_SCORE + t] = s;
        }
    }
}

__global__ __launch_bounds__(256) void lem_main(
    const int* __restrict__ seqs, const int* __restrict__ qtok,
    const float* __restrict__ rh_b2,
    const float* __restrict__ ws, float* __restrict__ out)
{
    __shared__ uint32_t MT2[2048];             // packed bf16 pairs [k/2][v]
    __shared__ float score_s[64];
    __shared__ unsigned long long tok_s[64];   // 8 surviving tokens, packed bytes
    __shared__ uint32_t hh2[2048];             // h bf16 pairs, [k/2][b]

    const int t = threadIdx.x;
    const int gbase = blockIdx.x * 64;
    const int lane = t & 63;
    const int w = t >> 6;                      // wave 0..3
    const int col = t & 31;
    const int half = (t >> 5) & 1;
    const int tile_n = w & 1;
    const int tile_m = w >> 1;

    // -------- pre-barrier prefetch (hidden behind the scan) --------
    // B fragments + bias
    uint4 bq[4];
    const uint4* B4 = (const uint4*)((const uint32_t*)ws + WS_W2B);
    #pragma unroll
    for (int kt = 0; kt < 4; ++kt)
        bq[kt] = B4[(kt * 2 + tile_n) * 64 + lane];
    const float bias = rh_b2[tile_n * 32 + col];
    // Q row slice for this wave's k-range (depends only on qtok, not the scan)
    const int qb = qtok[gbase + lane];
    float4 qreg[4];
    {
        const float4* Q4 = (const float4*)(ws + WS_Q1B);
        const int qbase = (qb * 64 + w * 16) >> 2;
        #pragma unroll
        for (int j4 = 0; j4 < 4; ++j4) qreg[j4] = Q4[qbase + j4];
    }

    if (w == 0) {
        // -------- wave 0: scores + eviction scan (one batch per lane) --------
        score_s[lane] = ws[WS_SCORE + lane];   // wave-internal: no barrier needed
        const int b = gbase + lane;
        int tk[SEQ_LEN];
        const int4* sq4 = (const int4*)(seqs + (long long)b * SEQ_LEN);
        #pragma unroll
        for (int r = 0; r < SEQ_LEN / 4; ++r) {
            int4 v = sq4[r];
            tk[r * 4 + 0] = v.x; tk[r * 4 + 1] = v.y;
            tk[r * 4 + 2] = v.z; tk[r * 4 + 3] = v.w;
        }
        int tok[MEM_SLOTS]; float sc[MEM_SLOTS];
        #pragma unroll
        for (int j = 0; j < MEM_SLOTS; ++j) tok[j] = tk[j];
        #pragma unroll
        for (int j = 0; j < MEM_SLOTS; ++j) sc[j] = score_s[tok[j]];
        #pragma unroll
        for (int step = MEM_SLOTS; step < SEQ_LEN - 1; ++step) {
            const int nt = tk[step];
            const float ns = score_s[nt];
            // first-index argmin (strict <) == jnp.argmin tie rule
            float bv = sc[0]; int be = 0;
            #pragma unroll
            for (int j = 1; j < MEM_SLOTS; ++j) {
                const bool lt = sc[j] < bv;
                bv = lt ? sc[j] : bv;
                be = lt ? j : be;
            }
            #pragma unroll
            for (int j = 0; j < MEM_SLOTS - 1; ++j) {
                const bool take = (j >= be);
                sc[j]  = take ? sc[j + 1]  : sc[j];
                tok[j] = take ? tok[j + 1] : tok[j];
            }
            sc[MEM_SLOTS - 1] = ns;
            tok[MEM_SLOTS - 1] = nt;
        }
        unsigned long long pk = 0ull;
        #pragma unroll
        for (int j = 0; j < MEM_SLOTS; ++j)
            pk |= (unsigned long long)(tok[j] & 255) << (8 * j);
        tok_s[lane] = pk;
    } else {
        // -------- waves 1-3: stage MT2 (8 KB) concurrently with the scan -----
        const uint4* src = (const uint4*)((const uint32_t*)ws + WS_M2P);
        uint4* dst = (uint4*)MT2;
        for (int i = t - 64; i < 512; i += 192) dst[i] = src[i];
    }
    __syncthreads();

    // -------- layer 1: h[w*16 .. +16)[b] = relu(Q1b[qb] + sum_j M1s[tok_j]) ---
    const int b = lane;
    const unsigned long long pk = tok_s[b];

    float acc[16];
    #pragma unroll
    for (int j4 = 0; j4 < 4; ++j4) {
        acc[j4 * 4 + 0] = qreg[j4].x; acc[j4 * 4 + 1] = qreg[j4].y;
        acc[j4 * 4 + 2] = qreg[j4].z; acc[j4 * 4 + 3] = qreg[j4].w;
    }
    #pragma unroll
    for (int j = 0; j < MEM_SLOTS; ++j) {
        const int tkn = (int)((pk >> (8 * j)) & 255);
        #pragma unroll
        for (int jj = 0; jj < 8; ++jj) {
            const uint32_t u = MT2[(w * 8 + jj) * 64 + tkn]; // bank=tkn%32: conflict-free
            acc[2 * jj + 0] += __uint_as_float(u << 16);
            acc[2 * jj + 1] += __uint_as_float(u & 0xFFFF0000u);
        }
    }
    // relu -> bf16 pairs -> hh2[k/2][b] (bank = b%32: conflict-free)
    #pragma unroll
    for (int jj = 0; jj < 8; ++jj) {
        const uint32_t lo = (__float_as_uint(fmaxf(acc[2 * jj + 0], 0.f)) + 0x8000u) >> 16;
        const uint32_t hi = (__float_as_uint(fmaxf(acc[2 * jj + 1], 0.f)) + 0x8000u) >> 16;
        hh2[(w * 8 + jj) * 64 + b] = lo | (hi << 16);
    }
    __syncthreads();

    // -------- layer 2: MFMA. C[m=batch(32)][n=out(32)] per wave, 4 K-steps ---
    floatx16 oacc;
    #pragma unroll
    for (int i = 0; i < 16; ++i) oacc[i] = bias;

    union U8 { uint32_t u[4]; short8 s; };
    #pragma unroll
    for (int kt = 0; kt < 4; ++kt) {
        U8 a;
        #pragma unroll
        for (int d = 0; d < 4; ++d)
            a.u[d] = hh2[(kt * 8 + half * 4 + d) * 64 + (tile_m * 32 + col)];
        U8 bb;
        bb.u[0] = bq[kt].x; bb.u[1] = bq[kt].y;
        bb.u[2] = bq[kt].z; bb.u[3] = bq[kt].w;
        oacc = __builtin_amdgcn_mfma_f32_32x32x16_bf16(a.s, bb.s, oacc, 0, 0, 0);
    }

    // store: row=(reg&3)+8*(reg>>2)+4*half, col=lane&31 (m74/m101-verified)
    #pragma unroll
    for (int reg = 0; reg < 16; ++reg) {
        const int row = (reg & 3) + 8 * (reg >> 2) + 4 * half;
        out[(long long)(gbase + tile_m * 32 + row) * 64 + tile_n * 32 + col] = oacc[reg];
    }
}

extern "C" void kernel_launch(void* const* d_in, const int* in_sizes, int n_in,
                              void* d_out, int out_size, void* d_ws, size_t ws_size,
                              hipStream_t stream)
{
    const int*   seqs   = (const int*)d_in[0];
    const int*   qtok   = (const int*)d_in[1];
    const float* embed  = (const float*)d_in[2];
    const float* sc_w1  = (const float*)d_in[3];
    const float* sc_b1  = (const float*)d_in[4];
    const float* sc_w2  = (const float*)d_in[5];
    const float* sc_b2  = (const float*)d_in[6];
    const float* rh_w1  = (const float*)d_in[7];
    const float* rh_b1  = (const float*)d_in[8];
    const float* rh_w2  = (const float*)d_in[9];
    const float* rh_b2  = (const float*)d_in[10];
    float* out = (float*)d_out;
    float* ws  = (float*)d_ws;

    const int B = in_sizes[1];   // 32768

    lem_precompute<<<25, 256, 0, stream>>>(embed, sc_w1, sc_b1, sc_w2, sc_b2,
                                           rh_w1, rh_b1, rh_w2, ws);
    lem_main<<<B / 64, 256, 0, stream>>>(seqs, qtok, rh_b2, ws, out);
}